// Round 16
// baseline (367.197 us; speedup 1.0000x reference)
//
#include <hip/hip_runtime.h>
#include <cstdint>
#include <cstddef>

// Problem constants (fixed by setup_inputs)
constexpr int kB  = 2;        // batch
constexpr int kQ  = 100;      // queries
constexpr int kN  = 200000;   // points
constexpr int kI  = 64;       // instances
constexpr int kC1 = 6;        // classes + 1 (no-object)
constexpr int kQP = 128;      // padded column count (cols >= kQ cost 1e30)
constexpr int kPB = 32;       // prep blocks per batch

// ---------------------------------------------------------------------------
// prep v2: per-block PARTIAL histogram/first-idx (plain stores, no global
// atomics, no memset needed). cntPart/fiPart: [kB][kPB][kI].
// ---------------------------------------------------------------------------
__global__ void prep_kernel(const int* __restrict__ labels,
                            int* __restrict__ cntPart, int* __restrict__ fiPart) {
  const int b = blockIdx.y;
  const int tid = threadIdx.x;
  __shared__ int lcnt[kI], lmin[kI];
  if (tid < kI) { lcnt[tid] = 0; lmin[tid] = 0x7FFFFFFF; }
  __syncthreads();
  for (int n = blockIdx.x * blockDim.x + tid; n < kN; n += gridDim.x * blockDim.x) {
    int l = labels[(size_t)b * kN + n] & (kI - 1);
    atomicAdd(&lcnt[l], 1);
    atomicMin(&lmin[l], n);
  }
  __syncthreads();
  if (tid < kI) {
    int o = (b * kPB + blockIdx.x) * kI + tid;
    cntPart[o] = lcnt[tid];
    fiPart[o]  = lmin[tid];
  }
}

// ---------------------------------------------------------------------------
// bucket v5: segmented sums, ONE packed u64 LDS atomic per element
// (hi32 = fi signed scale 2^14, lo32 = pi). 32 per-HALF-WAVE copies to
// halve same-address atomic serialization. cnt summed from partials.
// ---------------------------------------------------------------------------
__global__ __launch_bounds__(1024) void bucket_kernel(
    const float* __restrict__ pm, const int* __restrict__ labels,
    const int* __restrict__ cntPart,
    float* __restrict__ fS, float* __restrict__ pS,
    float* __restrict__ negTot, float* __restrict__ pTot,
    float* __restrict__ costT) {
  const int q = blockIdx.x, b = blockIdx.y;
  const int tid = threadIdx.x;
  const int w = tid >> 5;                     // half-wave id 0..31
  constexpr float kScale = 16384.0f;          // 2^14
  constexpr double kInv  = 1.0 / 16384.0;

  __shared__ unsigned long long lS[32][kI];   // per-half-wave packed sums
  for (int t = tid; t < 32 * kI; t += 1024)
    ((unsigned long long*)lS)[t] = 0ull;
  __syncthreads();

  const float4* row4 = (const float4*)(pm + ((size_t)(b * kQ + q)) * kN);
  const int4*   lab4 = (const int4*)(labels + (size_t)b * kN);
  float negAcc = 0.f;
  constexpr int NV4 = kN / 4;

  for (int it = tid; it < NV4; it += 1024) {
    float4 xv = row4[it];
    int4   lv = lab4[it];
#define PROC(x_, l_) do {                                   \
      float x = (x_); int l = (l_) & (kI - 1);              \
      float xc = fminf(fmaxf(x, -60.f), 60.f);              \
      float t  = __expf(-xc);                               \
      float r  = 1.0f / (1.0f + t);   /* sigmoid(x) */      \
      float L  = __logf(1.0f + t);    /* softplus(-x) */    \
      float omp = t * r;              /* 1 - p */           \
      float pos = 0.25f * omp * omp * L;                    \
      float neg = 0.75f * r * r * (L + x);                  \
      int fi = __float2int_rn((pos - neg) * kScale);        \
      int pi = __float2int_rn(r * kScale);                  \
      unsigned long long pk =                               \
        (unsigned long long)(((long long)fi) << 32) +       \
        (unsigned long long)(unsigned int)pi;               \
      atomicAdd(&lS[w][l], pk);                             \
      negAcc += neg;                                        \
    } while (0)
    PROC(xv.x, lv.x); PROC(xv.y, lv.y); PROC(xv.z, lv.z); PROC(xv.w, lv.w);
#undef PROC
  }
  __syncthreads();

  __shared__ float ffS[kI], fpS[kI];
  if (tid < kI) {
    long long fsum = 0, psum = 0;
    for (int ww = 0; ww < 32; ++ww) {
      unsigned long long s = lS[ww][tid];
      fsum += (int)(s >> 32);                 // two's-complement hi word
      psum += (long long)(s & 0xFFFFFFFFull);
    }
    ffS[tid] = (float)((double)fsum * kInv);
    fpS[tid] = (float)((double)psum * kInv);
  }
  for (int off = 32; off; off >>= 1) negAcc += __shfl_down(negAcc, off);
  __shared__ float wsum[16];
  if ((tid & 63) == 0) wsum[tid >> 6] = negAcc;
  __syncthreads();
  __shared__ float s_negTot, s_pTot;
  if (tid == 0) {
    float s = 0.f;
    for (int ww = 0; ww < 16; ++ww) s += wsum[ww];
    s_negTot = s;
  }
  if (tid < kI) {
    float vv = fpS[tid];
    for (int off = 32; off; off >>= 1) vv += __shfl_down(vv, off);
    if (tid == 0) s_pTot = vv;
  }
  __syncthreads();

  if (tid < kI) {
    int cv = 0;
    for (int blk = 0; blk < kPB; ++blk)
      cv += cntPart[(b * kPB + blk) * kI + tid];
    float f = ffS[tid], pp = fpS[tid];
    int bq = b * kQ + q;
    fS[(size_t)bq * kI + tid] = f;
    pS[(size_t)bq * kI + tid] = pp;
    float cf = (f + s_negTot) * (1.0f / kN);
    float cd = 1.0f - (2.0f * pp + 1.0f) / (s_pTot + (float)cv + 1.0f);
    costT[(size_t)(b * kI + tid) * kQ + q] = cf + cd;
    if (tid == 0) { negTot[bq] = s_negTot; pTot[bq] = s_pTot; }
  }
}

// ---------------------------------------------------------------------------
// Hungarian v15 — r15 machinery with cross-lane hops collapsed:
//  * row_bcast15/31 DPP tail (0x142/0x143): reduce lands in lane 63; ONE
//    rlf replaces 4 rlf + 3 fminf + readfirstlane. Functional equivalence
//    of bcast vs rl64 tails evidenced by v5/v6 bit-identical outputs.
//    Untargeted lanes self-combine (identity for min; corrupted two-smallest
//    lanes never feed lane 63).
//  * augrowred in full-f32 (same quantized lattice as r13-r15 PASSING SAP):
//    min1/min2 = masked packed values -> zero rl64 per step (was 4).
//  * SAP round otherwise r15-verbatim (full-f32, interleaved cols, b64
//    fetch, prefetch, parallel greedy claim).
// CS lesson stands (v5-v7, v10): no dual warm starts.
// ---------------------------------------------------------------------------
template<int CTRL>
__device__ __forceinline__ int dpp_mov(int x) {
  return __builtin_amdgcn_update_dpp(x, x, CTRL, 0xF, 0xF, false);
}
template<int CTRL>
__device__ __forceinline__ float dpp_minf(float a) {
  int o = dpp_mov<CTRL>(__float_as_int(a));
  return fminf(a, __int_as_float(o));
}
__device__ __forceinline__ float rlf(float x, int l) {
  return __int_as_float(__builtin_amdgcn_readlane(__float_as_int(x), l));
}
__device__ __forceinline__ float packF(float v, int cid) {
  int bb = __float_as_int(v);
  bb = (bb & ~0x7F) | cid;
  return __int_as_float(bb);
}
__device__ __forceinline__ float maskF(float v) {          // id bits -> 0
  return __int_as_float(__float_as_int(v) & ~0x7F);
}
// two-smallest combine on packed f32 (value order; ids ride in low bits)
__device__ __forceinline__ void comb2f(float& m1, float& m2, float o1, float o2) {
  float lo = fminf(m1, o1);
  float hi = fmaxf(m1, o1);
  m2 = fminf(hi, fminf(m2, o2));
  m1 = lo;
}
template<int CTRL>
__device__ __forceinline__ void dpp_comb2f(float& m1, float& m2) {
  float o1 = __int_as_float(dpp_mov<CTRL>(__float_as_int(m1)));
  float o2 = __int_as_float(dpp_mov<CTRL>(__float_as_int(m2)));
  comb2f(m1, m2, o1, o2);
}

__global__ void hungarian_kernel(const float* __restrict__ costT,
                                 int* __restrict__ idx_q) {
  const int b = blockIdx.x;
  const int lane = threadIdx.x;  // 64 threads = 1 wave
  __shared__ float costL[kI * kQP];
  __shared__ int claim[kQP];
  for (int t = lane; t < kI * kQP; t += 64) {
    int row = t >> 7, col = t & (kQP - 1);
    costL[t] = (col < kQ) ? costT[(size_t)b * kI * kQ + row * kQ + col] : 1e30f;
  }
  claim[lane] = 127;
  claim[lane + 64] = 127;
  __syncthreads();

  const int col0 = 2 * lane, col1 = 2 * lane + 1;  // owned columns
  float v0f = 0.f, v1f = 0.f;    // v[col0], v[col1]
  int p0 = 0, p1 = 0;            // matched row (1-based) of col0, col1

  // --- JV init: u[row]=row min (f32 float4 scan, first-index tie-break) ---
  float m = 1e30f; int jm = 0;
  {
    const float4* r4 = (const float4*)&costL[lane * kQP];
    for (int k4 = 0; k4 < kQ / 4; ++k4) {
      float4 c = r4[k4];
      int k = 4 * k4;
      if (c.x < m) { m = c.x; jm = k; }
      if (c.y < m) { m = c.y; jm = k + 1; }
      if (c.z < m) { m = c.z; jm = k + 2; }
      if (c.w < m) { m = c.w; jm = k + 3; }
    }
  }
  float u_f = m;                              // u[lane+1]

  // --- parallel greedy claim: winner(col) = smallest row index ------------
  atomicMin(&claim[jm], lane);
  __syncthreads();
  unsigned long long rowM = __ballot(claim[jm] == lane);
  {
    int w0 = claim[col0], w1 = claim[col1];
    p0 = (w0 < 64) ? w0 + 1 : 0;
    p1 = (w1 < 64) ? w1 + 1 : 0;
  }

  // --- LAPJV augmenting row reduction (2 passes; full-f32 packed) ----------
  unsigned long long pool = ~rowM;            // unmatched rows (bit r = row r+1)
  unsigned long long leftover = 0ull;
  for (int pass = 0; pass < 2; ++pass) {
    unsigned long long next = 0ull;
    unsigned long long cur = pool;
    while (cur) {
      int i = __builtin_ctzll(cur) + 1;       // row, 1-based
      cur &= cur - 1;
      float2 cc = *(const float2*)&costL[(i - 1) * kQP + col0];
      float pf0 = packF(cc.x - v0f, col0);
      float pf1 = packF(cc.y - v1f, col1);    // padded cols ~1e30
      float m1 = fminf(pf0, pf1), m2 = fmaxf(pf0, pf1);
      dpp_comb2f<0xB1>(m1, m2);               // xor 1
      dpp_comb2f<0x4E>(m1, m2);               // xor 2
      dpp_comb2f<0x141>(m1, m2);              // xor 4
      dpp_comb2f<0x140>(m1, m2);              // xor 8
      dpp_comb2f<0x142>(m1, m2);              // row_bcast15 (rows 0->1, 2->3)
      dpp_comb2f<0x143>(m1, m2);              // row_bcast31 -> lane 63 global
      float a1 = rlf(m1, 63), a2 = rlf(m2, 63);
      int gi1 = __float_as_int(a1);
      int cid1 = gi1 & 0x7F;
      float min1 = __int_as_float(gi1 & ~0x7F);
      float min2 = maskF(a2);
      float dv = min2 - min1;                 // >= 0 (quantized lattice)
      int L1 = cid1 >> 1; bool sW = cid1 & 1;
      u_f = (lane == i - 1) ? min2 : u_f;     // u[i] = second minimum
      int i0 = sW ? __builtin_amdgcn_readlane(p1, L1)
                  : __builtin_amdgcn_readlane(p0, L1);
      bool mine0 = (!sW) && (lane == L1);
      bool mine1 = sW && (lane == L1);
      p0 = mine0 ? i : p0;  v0f -= mine0 ? dv : 0.f;
      p1 = mine1 ? i : p1;  v1f -= mine1 ? dv : 0.f;
      if (i0 != 0) {                          // kicked row -> later pass / SAP
        if (pass == 0) next |= 1ull << (i0 - 1);
        else           leftover |= 1ull << (i0 - 1);
      }
    }
    pool = next;
  }
  leftover |= pool;                           // (pool empty after pass 1)

  // --- exact SAP for leftover rows (full-f32, bcast tail) -------------------
  const float SENT = packF(1e30f, 127);
  for (int i = 1; i <= kI; ++i) {
    if (!((leftover >> (i - 1)) & 1ull)) continue;
    float minv0 = SENT, minv1 = SENT;   // packed (value | col id)
    int way0 = 0, way1 = 0;
    bool used0 = false, used1 = false;
    bool onpath = (lane == i - 1);
    int j0 = 0, j1 = 0;
    float2 cc = *(const float2*)&costL[(i - 1) * kQP + col0];
    float c0 = cc.x, c1 = cc.y;
    float ui0 = rlf(u_f, i - 1);
    for (int guard = 0; guard < 2 * kQ; ++guard) {
      float pk0 = packF(c0 - ui0 - v0f, col0);
      bool up0 = (!used0) && (pk0 < minv0);
      minv0 = up0 ? pk0 : minv0;
      way0  = up0 ? j0 : way0;
      float pk1 = packF(c1 - ui0 - v1f, col1);
      bool up1 = (!used1) && (pk1 < minv1);
      minv1 = up1 ? pk1 : minv1;
      way1  = up1 ? j0 : way1;
      // argmin butterfly on packed values -> global min in lane 63
      float bm = fminf(minv0, minv1);
      bm = dpp_minf<0xB1>(bm);    // xor 1
      bm = dpp_minf<0x4E>(bm);    // xor 2
      bm = dpp_minf<0x141>(bm);   // xor 4
      bm = dpp_minf<0x140>(bm);   // xor 8
      bm = dpp_minf<0x142>(bm);   // row_bcast15
      bm = dpp_minf<0x143>(bm);   // row_bcast31
      float g = rlf(bm, 63);
      int gi = __float_as_int(g);           // uniform
      int cid = gi & 0x7F;
      float delta = __int_as_float(gi & ~0x7F);   // quantized min value
      const int  L = cid >> 1;
      const bool s = cid & 1;
      int r1 = s ? __builtin_amdgcn_readlane(p1, L)
                 : __builtin_amdgcn_readlane(p0, L);
      // prefetch next row while updating duals
      int i0n = (r1 > 0) ? r1 : 1;
      float2 cn = *(const float2*)&costL[(i0n - 1) * kQP + col0];

      u_f += onpath ? delta : 0.f;
      v0f -= used0 ? delta : 0.f;
      v1f -= used1 ? delta : 0.f;
      minv0 = used0 ? minv0 : packF(maskF(minv0) - delta, col0);
      minv1 = used1 ? minv1 : packF(maskF(minv1) - delta, col1);
      bool w0 = (!s) && (lane == L);
      bool w1 = s && (lane == L);
      used0 = used0 || w0;
      used1 = used1 || w1;
      minv0 = w0 ? SENT : minv0;
      minv1 = w1 ? SENT : minv1;
      j1 = cid + 1;                 // 1-based col id for augment chain

      if (r1 == 0) break;           // free column reached
      onpath = onpath || (lane == r1 - 1);
      ui0 = rlf(u_f, r1 - 1);       // prefetched for next round
      j0 = j1;
      c0 = cn.x;
      c1 = cn.y;
    }
    // augment along way-chain (all indices/values uniform)
    int jc = j1;
    while (jc) {
      int Lc = (jc - 1) >> 1, sc = (jc - 1) & 1;
      int jw = sc ? __builtin_amdgcn_readlane(way1, Lc)
                  : __builtin_amdgcn_readlane(way0, Lc);
      int pw;
      if (jw == 0) pw = i;
      else {
        int Lw = (jw - 1) >> 1, sw = (jw - 1) & 1;
        pw = sw ? __builtin_amdgcn_readlane(p1, Lw)
                : __builtin_amdgcn_readlane(p0, Lw);
      }
      bool w0 = (!sc) && (lane == Lc);
      bool w1 = sc && (lane == Lc);
      p0 = w0 ? pw : p0;
      p1 = w1 ? pw : p1;
      jc = jw;
    }
  }
  if (col0 < kQ && p0 > 0) idx_q[b * kI + (p0 - 1)] = col0;
  if (col1 < kQ && p1 > 0) idx_q[b * kI + (p1 - 1)] = col1;
}

// ---------------------------------------------------------------------------
// final loss from bucket sums + matching (cnt/firstIdx from partials)
// ---------------------------------------------------------------------------
__device__ __forceinline__ float reduce128(float v, float* scratch, int tid) {
  for (int off = 32; off; off >>= 1) v += __shfl_down(v, off);
  __syncthreads();
  if ((tid & 63) == 0) scratch[tid >> 6] = v;
  __syncthreads();
  return scratch[0] + scratch[1];
}

__global__ void loss_kernel(const float* __restrict__ logits, const int* __restrict__ seg,
                            const float* __restrict__ fS, const float* __restrict__ pS,
                            const float* __restrict__ negTot, const float* __restrict__ pTot,
                            const int* __restrict__ cntPart, const int* __restrict__ fiPart,
                            const int* __restrict__ idx_q, float* __restrict__ out) {
  const int tid = threadIdx.x;  // 128
  __shared__ float lse[kQ];
  __shared__ int matched[kQ];
  __shared__ float scratch[2];
  float total = 0.f;
  for (int b = 0; b < kB; ++b) {
    if (tid < kQ) {
      const float* lr = logits + (size_t)(b * kQ + tid) * kC1;
      float m = lr[0];
#pragma unroll
      for (int c = 1; c < kC1; ++c) m = fmaxf(m, lr[c]);
      float s = 0.f;
#pragma unroll
      for (int c = 0; c < kC1; ++c) s += __expf(lr[c] - m);
      lse[tid] = m + __logf(s);
      matched[tid] = 0;
    }
    __syncthreads();
    if (tid < kI) matched[idx_q[b * kI + tid]] = 1;
    __syncthreads();

    float fo = 0.f, di = 0.f, cm = 0.f, no = 0.f, nu = 0.f;
    if (tid < kI) {
      int cv = 0, fi = 0x7FFFFFFF;
      for (int blk = 0; blk < kPB; ++blk) {
        int o = (b * kPB + blk) * kI + tid;
        cv += cntPart[o];
        fi = min(fi, fiPart[o]);
      }
      int qi = idx_q[b * kI + tid];
      int bq = b * kQ + qi;
      float f = fS[(size_t)bq * kI + tid];
      fo = f + negTot[bq];
      float pp = pS[(size_t)bq * kI + tid];
      di = 1.f - (2.f * pp + 1.f) / (pTot[bq] + (float)cv + 1.f);
      fi = fi < kN ? fi : kN - 1;
      int ci = seg[(size_t)b * kN + fi];
      ci = ci < 0 ? 0 : (ci > kC1 - 2 ? kC1 - 2 : ci);  // clip(·,0,C-1)
      cm = logits[(size_t)bq * kC1 + ci] - lse[qi];
    }
    if (tid < kQ && !matched[tid]) {
      no = logits[(size_t)(b * kQ + tid) * kC1 + (kC1 - 1)] - lse[tid];
      nu = 1.f;
    }
    float foS = reduce128(fo, scratch, tid);
    float diS = reduce128(di, scratch, tid);
    float cmS = reduce128(cm, scratch, tid);
    float noS = reduce128(no, scratch, tid);
    float nuS = reduce128(nu, scratch, tid);

    float focal = foS / ((float)kI * (float)kN);
    float dice  = diS / (float)kI;
    float cem   = -cmS / (float)kI;
    float cen   = -noS / fmaxf(nuS, 1.f);
    total += focal + dice + 2.0f * cem + 0.1f * cen;
    __syncthreads();
  }
  if (tid == 0) out[0] = total * (1.0f / kB);
}

// ---------------------------------------------------------------------------
extern "C" void kernel_launch(void* const* d_in, const int* in_sizes, int n_in,
                              void* d_out, int out_size, void* d_ws, size_t ws_size,
                              hipStream_t stream) {
  const float* pm     = (const float*)d_in[0];  // [B,Q,N]
  const float* logits = (const float*)d_in[1];  // [B,Q,C1]
  const int*   labels = (const int*)d_in[2];    // [B,N]
  const int*   seg    = (const int*)d_in[3];    // [B,N]

  char* w = (char*)d_ws;
  float* fS       = (float*)w; w += (size_t)kB * kQ * kI * 4;
  float* pS       = (float*)w; w += (size_t)kB * kQ * kI * 4;
  float* negTot   = (float*)w; w += (size_t)kB * kQ * 4;
  float* pTot     = (float*)w; w += (size_t)kB * kQ * 4;
  float* costT    = (float*)w; w += (size_t)kB * kI * kQ * 4;
  int*   cntPart  = (int*)w;   w += (size_t)kB * kPB * kI * 4;
  int*   fiPart   = (int*)w;   w += (size_t)kB * kPB * kI * 4;
  int*   idx_q    = (int*)w;   w += (size_t)kB * kI * 4;

  prep_kernel<<<dim3(kPB, kB), 256, 0, stream>>>(labels, cntPart, fiPart);
  bucket_kernel<<<dim3(kQ, kB), 1024, 0, stream>>>(pm, labels, cntPart, fS, pS,
                                                   negTot, pTot, costT);
  hungarian_kernel<<<kB, 64, 0, stream>>>(costT, idx_q);
  loss_kernel<<<1, 128, 0, stream>>>(logits, seg, fS, pS, negTot, pTot,
                                     cntPart, fiPart, idx_q, (float*)d_out);
}

// Round 17
// 355.388 us; speedup vs baseline: 1.0332x; 1.0332x over previous
//
#include <hip/hip_runtime.h>
#include <cstdint>
#include <cstddef>

// Problem constants (fixed by setup_inputs)
constexpr int kB  = 2;        // batch
constexpr int kQ  = 100;      // queries
constexpr int kN  = 200000;   // points
constexpr int kI  = 64;       // instances
constexpr int kC1 = 6;        // classes + 1 (no-object)
constexpr int kQP = 128;      // padded column count (cols >= kQ cost 1e30)
constexpr int kPB = 32;       // prep blocks per batch

// ---------------------------------------------------------------------------
// prep v2: per-block PARTIAL histogram/first-idx (plain stores, no global
// atomics, no memset needed). cntPart/fiPart: [kB][kPB][kI].
// ---------------------------------------------------------------------------
__global__ void prep_kernel(const int* __restrict__ labels,
                            int* __restrict__ cntPart, int* __restrict__ fiPart) {
  const int b = blockIdx.y;
  const int tid = threadIdx.x;
  __shared__ int lcnt[kI], lmin[kI];
  if (tid < kI) { lcnt[tid] = 0; lmin[tid] = 0x7FFFFFFF; }
  __syncthreads();
  for (int n = blockIdx.x * blockDim.x + tid; n < kN; n += gridDim.x * blockDim.x) {
    int l = labels[(size_t)b * kN + n] & (kI - 1);
    atomicAdd(&lcnt[l], 1);
    atomicMin(&lmin[l], n);
  }
  __syncthreads();
  if (tid < kI) {
    int o = (b * kPB + blockIdx.x) * kI + tid;
    cntPart[o] = lcnt[tid];
    fiPart[o]  = lmin[tid];
  }
}

// ---------------------------------------------------------------------------
// bucket v4: segmented sums, ONE packed u64 LDS atomic per element
// (hi32 = fi signed scale 2^14, lo32 = pi). cnt summed from partials.
// ---------------------------------------------------------------------------
__global__ __launch_bounds__(1024) void bucket_kernel(
    const float* __restrict__ pm, const int* __restrict__ labels,
    const int* __restrict__ cntPart,
    float* __restrict__ fS, float* __restrict__ pS,
    float* __restrict__ negTot, float* __restrict__ pTot,
    float* __restrict__ costT) {
  const int q = blockIdx.x, b = blockIdx.y;
  const int tid = threadIdx.x;
  const int w = tid >> 6;
  constexpr float kScale = 16384.0f;          // 2^14
  constexpr double kInv  = 1.0 / 16384.0;

  __shared__ unsigned long long lS[16][kI];   // per-wave packed (fi<<32)+pi
  ((unsigned long long*)lS)[tid] = 0ull;      // 16*64 == 1024
  __syncthreads();

  const float4* row4 = (const float4*)(pm + ((size_t)(b * kQ + q)) * kN);
  const int4*   lab4 = (const int4*)(labels + (size_t)b * kN);
  float negAcc = 0.f;
  constexpr int NV4 = kN / 4;

  for (int it = tid; it < NV4; it += 1024) {
    float4 xv = row4[it];
    int4   lv = lab4[it];
#define PROC(x_, l_) do {                                   \
      float x = (x_); int l = (l_) & (kI - 1);              \
      float xc = fminf(fmaxf(x, -60.f), 60.f);              \
      float t  = __expf(-xc);                               \
      float r  = 1.0f / (1.0f + t);   /* sigmoid(x) */      \
      float L  = __logf(1.0f + t);    /* softplus(-x) */    \
      float omp = t * r;              /* 1 - p */           \
      float pos = 0.25f * omp * omp * L;                    \
      float neg = 0.75f * r * r * (L + x);                  \
      int fi = __float2int_rn((pos - neg) * kScale);        \
      int pi = __float2int_rn(r * kScale);                  \
      unsigned long long pk =                               \
        (unsigned long long)(((long long)fi) << 32) +       \
        (unsigned long long)(unsigned int)pi;               \
      atomicAdd(&lS[w][l], pk);                             \
      negAcc += neg;                                        \
    } while (0)
    PROC(xv.x, lv.x); PROC(xv.y, lv.y); PROC(xv.z, lv.z); PROC(xv.w, lv.w);
#undef PROC
  }
  __syncthreads();

  __shared__ float ffS[kI], fpS[kI];
  if (tid < kI) {
    long long fsum = 0, psum = 0;
    for (int ww = 0; ww < 16; ++ww) {
      unsigned long long s = lS[ww][tid];
      fsum += (int)(s >> 32);                 // two's-complement hi word
      psum += (long long)(s & 0xFFFFFFFFull);
    }
    ffS[tid] = (float)((double)fsum * kInv);
    fpS[tid] = (float)((double)psum * kInv);
  }
  for (int off = 32; off; off >>= 1) negAcc += __shfl_down(negAcc, off);
  __shared__ float wsum[16];
  if ((tid & 63) == 0) wsum[w] = negAcc;
  __syncthreads();
  __shared__ float s_negTot, s_pTot;
  if (tid == 0) {
    float s = 0.f;
    for (int ww = 0; ww < 16; ++ww) s += wsum[ww];
    s_negTot = s;
  }
  if (tid < kI) {
    float vv = fpS[tid];
    for (int off = 32; off; off >>= 1) vv += __shfl_down(vv, off);
    if (tid == 0) s_pTot = vv;
  }
  __syncthreads();

  if (tid < kI) {
    int cv = 0;
    for (int blk = 0; blk < kPB; ++blk)
      cv += cntPart[(b * kPB + blk) * kI + tid];
    float f = ffS[tid], pp = fpS[tid];
    int bq = b * kQ + q;
    fS[(size_t)bq * kI + tid] = f;
    pS[(size_t)bq * kI + tid] = pp;
    float cf = (f + s_negTot) * (1.0f / kN);
    float cd = 1.0f - (2.0f * pp + 1.0f) / (s_pTot + (float)cv + 1.0f);
    costT[(size_t)(b * kI + tid) * kQ + q] = cf + cd;
    if (tid == 0) { negTot[bq] = s_negTot; pTot[bq] = s_pTot; }
  }
}

// ---------------------------------------------------------------------------
// Hungarian v14 (r15-proven, 265us, absmax 0) — full-f32 SAP; f32-select +
// exact-f64 augrowred; interleaved column ownership (lane owns cols 2L,
// 2L+1 -> one ds_read_b64 per row fetch); float4 init scan; PARALLEL
// greedy claim (LDS atomicMin); rl64-tail reduces (r16's bcast tail
// REGRESSED — dependent DPP levels cost more than parallel readlanes on
// this latency-bound chain).
// CS lesson stands (v5-v7, v10): no dual warm starts.
// ---------------------------------------------------------------------------
template<int CTRL>
__device__ __forceinline__ int dpp_mov(int x) {
  return __builtin_amdgcn_update_dpp(x, x, CTRL, 0xF, 0xF, false);
}
template<int CTRL>
__device__ __forceinline__ float dpp_minf(float a) {
  int o = dpp_mov<CTRL>(__float_as_int(a));
  return fminf(a, __int_as_float(o));
}
__device__ __forceinline__ double rl64(double x, int l) {
  int lo = __builtin_amdgcn_readlane(__double2loint(x), l);
  int hi = __builtin_amdgcn_readlane(__double2hiint(x), l);
  return __hiloint2double(hi, lo);
}
__device__ __forceinline__ float rlf(float x, int l) {
  return __int_as_float(__builtin_amdgcn_readlane(__float_as_int(x), l));
}
__device__ __forceinline__ float packF(float v, int cid) {
  int bb = __float_as_int(v);
  bb = (bb & ~0x7F) | cid;
  return __int_as_float(bb);
}
__device__ __forceinline__ float maskF(float v) {          // id bits -> 0
  return __int_as_float(__float_as_int(v) & ~0x7F);
}
// two-smallest combine on packed f32 (value order; ids ride in low bits)
__device__ __forceinline__ void comb2f(float& m1, float& m2, float o1, float o2) {
  float lo = fminf(m1, o1);
  float hi = fmaxf(m1, o1);
  m2 = fminf(hi, fminf(m2, o2));
  m1 = lo;
}
template<int CTRL>
__device__ __forceinline__ void dpp_comb2f(float& m1, float& m2) {
  float o1 = __int_as_float(dpp_mov<CTRL>(__float_as_int(m1)));
  float o2 = __int_as_float(dpp_mov<CTRL>(__float_as_int(m2)));
  comb2f(m1, m2, o1, o2);
}

__global__ void hungarian_kernel(const float* __restrict__ costT,
                                 int* __restrict__ idx_q) {
  const int b = blockIdx.x;
  const int lane = threadIdx.x;  // 64 threads = 1 wave
  __shared__ float costL[kI * kQP];
  __shared__ int claim[kQP];
  for (int t = lane; t < kI * kQP; t += 64) {
    int row = t >> 7, col = t & (kQP - 1);
    costL[t] = (col < kQ) ? costT[(size_t)b * kI * kQ + row * kQ + col] : 1e30f;
  }
  claim[lane] = 127;
  claim[lane + 64] = 127;
  __syncthreads();

  const int col0 = 2 * lane, col1 = 2 * lane + 1;  // owned columns
  double v0 = 0.0, v1 = 0.0;     // v[col0], v[col1]
  int p0 = 0, p1 = 0;            // matched row (1-based) of col0, col1

  // --- JV init: u[row]=row min (float4 scan, first-index tie-break) -------
  double m = 1e18; int jm = 0;
  {
    const float4* r4 = (const float4*)&costL[lane * kQP];
    for (int k4 = 0; k4 < kQ / 4; ++k4) {
      float4 c = r4[k4];
      int k = 4 * k4;
      if ((double)c.x < m) { m = (double)c.x; jm = k; }
      if ((double)c.y < m) { m = (double)c.y; jm = k + 1; }
      if ((double)c.z < m) { m = (double)c.z; jm = k + 2; }
      if ((double)c.w < m) { m = (double)c.w; jm = k + 3; }
    }
  }
  double u_r = m;                             // u[lane+1]

  // --- parallel greedy claim: winner(col) = smallest row index ------------
  atomicMin(&claim[jm], lane);
  __syncthreads();
  unsigned long long rowM = __ballot(claim[jm] == lane);
  {
    int w0 = claim[col0], w1 = claim[col1];
    p0 = (w0 < 64) ? w0 + 1 : 0;
    p1 = (w1 < 64) ? w1 + 1 : 0;
  }

  // --- LAPJV augmenting row reduction (2 passes; f32 select + exact f64) ---
  unsigned long long pool = ~rowM;            // unmatched rows (bit r = row r+1)
  unsigned long long leftover = 0ull;
  for (int pass = 0; pass < 2; ++pass) {
    unsigned long long next = 0ull;
    unsigned long long cur = pool;
    while (cur) {
      int i = __builtin_ctzll(cur) + 1;       // row, 1-based
      cur &= cur - 1;
      float2 cc = *(const float2*)&costL[(i - 1) * kQP + col0];
      double e0 = (double)cc.x - v0;
      double e1 = (double)cc.y - v1;          // padded cols ~1e30
      float pf0 = packF((float)e0, col0);
      float pf1 = packF((float)e1, col1);
      float m1 = fminf(pf0, pf1), m2 = fmaxf(pf0, pf1);
      dpp_comb2f<0xB1>(m1, m2);               // xor 1
      dpp_comb2f<0x4E>(m1, m2);               // xor 2
      dpp_comb2f<0x141>(m1, m2);              // xor 4
      dpp_comb2f<0x140>(m1, m2);              // xor 8
      float a1 = rlf(m1, 0),  a2 = rlf(m2, 0);
      { float b1 = rlf(m1, 16), b2 = rlf(m2, 16); comb2f(a1, a2, b1, b2); }
      { float b1 = rlf(m1, 32), b2 = rlf(m2, 32); comb2f(a1, a2, b1, b2); }
      { float b1 = rlf(m1, 48), b2 = rlf(m2, 48); comb2f(a1, a2, b1, b2); }
      int cid1 = __builtin_amdgcn_readfirstlane(__float_as_int(a1) & 0x7F);
      int cid2 = __builtin_amdgcn_readfirstlane(__float_as_int(a2) & 0x7F);
      int L1 = cid1 >> 1; bool sW = cid1 & 1;
      int L2 = cid2 >> 1; bool sW2 = cid2 & 1;
      double min1 = sW  ? rl64(e1, L1) : rl64(e0, L1);   // EXACT values
      double min2 = sW2 ? rl64(e1, L2) : rl64(e0, L2);
      double dv = min2 - min1;
      u_r = (lane == i - 1) ? min2 : u_r;     // u[i] = second minimum
      int i0 = sW ? __builtin_amdgcn_readlane(p1, L1)
                  : __builtin_amdgcn_readlane(p0, L1);
      bool mine0 = (!sW) && (lane == L1);
      bool mine1 = sW && (lane == L1);
      p0 = mine0 ? i : p0;  v0 -= mine0 ? dv : 0.0;
      p1 = mine1 ? i : p1;  v1 -= mine1 ? dv : 0.0;
      if (i0 != 0) {                          // kicked row -> later pass / SAP
        if (pass == 0) next |= 1ull << (i0 - 1);
        else           leftover |= 1ull << (i0 - 1);
      }
    }
    pool = next;
  }
  leftover |= pool;                           // (pool empty after pass 1)

  // --- exact SAP for leftover rows (full-f32 packed round, b64 row fetch) --
  const float SENT = packF(1e30f, 127);
  float u_f  = (float)u_r;
  float v0f  = (float)v0;
  float v1f  = (float)v1;
  for (int i = 1; i <= kI; ++i) {
    if (!((leftover >> (i - 1)) & 1ull)) continue;
    float minv0 = SENT, minv1 = SENT;   // packed (value | col id)
    int way0 = 0, way1 = 0;
    bool used0 = false, used1 = false;
    bool onpath = (lane == i - 1);
    int j0 = 0, j1 = 0;
    float2 cc = *(const float2*)&costL[(i - 1) * kQP + col0];
    float c0 = cc.x, c1 = cc.y;
    float ui0 = rlf(u_f, i - 1);
    for (int guard = 0; guard < 2 * kQ; ++guard) {
      float pk0 = packF(c0 - ui0 - v0f, col0);
      bool up0 = (!used0) && (pk0 < minv0);
      minv0 = up0 ? pk0 : minv0;
      way0  = up0 ? j0 : way0;
      float pk1 = packF(c1 - ui0 - v1f, col1);
      bool up1 = (!used1) && (pk1 < minv1);
      minv1 = up1 ? pk1 : minv1;
      way1  = up1 ? j0 : way1;
      // argmin butterfly on packed values (used slots already SENT)
      float bm = fminf(minv0, minv1);
      bm = dpp_minf<0xB1>(bm);    // xor 1
      bm = dpp_minf<0x4E>(bm);    // xor 2
      bm = dpp_minf<0x141>(bm);   // xor 4
      bm = dpp_minf<0x140>(bm);   // xor 8
      float g = fminf(fminf(rlf(bm, 0), rlf(bm, 16)),
                      fminf(rlf(bm, 32), rlf(bm, 48)));
      int gi = __builtin_amdgcn_readfirstlane(__float_as_int(g));
      int cid = gi & 0x7F;
      float delta = __int_as_float(gi & ~0x7F);   // quantized min value
      const int  L = cid >> 1;
      const bool s = cid & 1;
      int r1 = s ? __builtin_amdgcn_readlane(p1, L)
                 : __builtin_amdgcn_readlane(p0, L);
      // prefetch next row while updating duals
      int i0n = (r1 > 0) ? r1 : 1;
      float2 cn = *(const float2*)&costL[(i0n - 1) * kQP + col0];

      u_f += onpath ? delta : 0.f;
      v0f -= used0 ? delta : 0.f;
      v1f -= used1 ? delta : 0.f;
      minv0 = used0 ? minv0 : packF(maskF(minv0) - delta, col0);
      minv1 = used1 ? minv1 : packF(maskF(minv1) - delta, col1);
      bool w0 = (!s) && (lane == L);
      bool w1 = s && (lane == L);
      used0 = used0 || w0;
      used1 = used1 || w1;
      minv0 = w0 ? SENT : minv0;
      minv1 = w1 ? SENT : minv1;
      j1 = cid + 1;                 // 1-based col id for augment chain

      if (r1 == 0) break;           // free column reached
      onpath = onpath || (lane == r1 - 1);
      ui0 = rlf(u_f, r1 - 1);       // prefetched for next round
      j0 = j1;
      c0 = cn.x;
      c1 = cn.y;
    }
    // augment along way-chain (all indices/values uniform)
    int jc = j1;
    while (jc) {
      int Lc = (jc - 1) >> 1, sc = (jc - 1) & 1;
      int jw = sc ? __builtin_amdgcn_readlane(way1, Lc)
                  : __builtin_amdgcn_readlane(way0, Lc);
      int pw;
      if (jw == 0) pw = i;
      else {
        int Lw = (jw - 1) >> 1, sw = (jw - 1) & 1;
        pw = sw ? __builtin_amdgcn_readlane(p1, Lw)
                : __builtin_amdgcn_readlane(p0, Lw);
      }
      bool w0 = (!sc) && (lane == Lc);
      bool w1 = sc && (lane == Lc);
      p0 = w0 ? pw : p0;
      p1 = w1 ? pw : p1;
      jc = jw;
    }
  }
  if (col0 < kQ && p0 > 0) idx_q[b * kI + (p0 - 1)] = col0;
  if (col1 < kQ && p1 > 0) idx_q[b * kI + (p1 - 1)] = col1;
}

// ---------------------------------------------------------------------------
// final loss from bucket sums + matching (cnt/firstIdx from partials)
// ---------------------------------------------------------------------------
__device__ __forceinline__ float reduce128(float v, float* scratch, int tid) {
  for (int off = 32; off; off >>= 1) v += __shfl_down(v, off);
  __syncthreads();
  if ((tid & 63) == 0) scratch[tid >> 6] = v;
  __syncthreads();
  return scratch[0] + scratch[1];
}

__global__ void loss_kernel(const float* __restrict__ logits, const int* __restrict__ seg,
                            const float* __restrict__ fS, const float* __restrict__ pS,
                            const float* __restrict__ negTot, const float* __restrict__ pTot,
                            const int* __restrict__ cntPart, const int* __restrict__ fiPart,
                            const int* __restrict__ idx_q, float* __restrict__ out) {
  const int tid = threadIdx.x;  // 128
  __shared__ float lse[kQ];
  __shared__ int matched[kQ];
  __shared__ float scratch[2];
  float total = 0.f;
  for (int b = 0; b < kB; ++b) {
    if (tid < kQ) {
      const float* lr = logits + (size_t)(b * kQ + tid) * kC1;
      float m = lr[0];
#pragma unroll
      for (int c = 1; c < kC1; ++c) m = fmaxf(m, lr[c]);
      float s = 0.f;
#pragma unroll
      for (int c = 0; c < kC1; ++c) s += __expf(lr[c] - m);
      lse[tid] = m + __logf(s);
      matched[tid] = 0;
    }
    __syncthreads();
    if (tid < kI) matched[idx_q[b * kI + tid]] = 1;
    __syncthreads();

    float fo = 0.f, di = 0.f, cm = 0.f, no = 0.f, nu = 0.f;
    if (tid < kI) {
      int cv = 0, fi = 0x7FFFFFFF;
      for (int blk = 0; blk < kPB; ++blk) {
        int o = (b * kPB + blk) * kI + tid;
        cv += cntPart[o];
        fi = min(fi, fiPart[o]);
      }
      int qi = idx_q[b * kI + tid];
      int bq = b * kQ + qi;
      float f = fS[(size_t)bq * kI + tid];
      fo = f + negTot[bq];
      float pp = pS[(size_t)bq * kI + tid];
      di = 1.f - (2.f * pp + 1.f) / (pTot[bq] + (float)cv + 1.f);
      fi = fi < kN ? fi : kN - 1;
      int ci = seg[(size_t)b * kN + fi];
      ci = ci < 0 ? 0 : (ci > kC1 - 2 ? kC1 - 2 : ci);  // clip(·,0,C-1)
      cm = logits[(size_t)bq * kC1 + ci] - lse[qi];
    }
    if (tid < kQ && !matched[tid]) {
      no = logits[(size_t)(b * kQ + tid) * kC1 + (kC1 - 1)] - lse[tid];
      nu = 1.f;
    }
    float foS = reduce128(fo, scratch, tid);
    float diS = reduce128(di, scratch, tid);
    float cmS = reduce128(cm, scratch, tid);
    float noS = reduce128(no, scratch, tid);
    float nuS = reduce128(nu, scratch, tid);

    float focal = foS / ((float)kI * (float)kN);
    float dice  = diS / (float)kI;
    float cem   = -cmS / (float)kI;
    float cen   = -noS / fmaxf(nuS, 1.f);
    total += focal + dice + 2.0f * cem + 0.1f * cen;
    __syncthreads();
  }
  if (tid == 0) out[0] = total * (1.0f / kB);
}

// ---------------------------------------------------------------------------
extern "C" void kernel_launch(void* const* d_in, const int* in_sizes, int n_in,
                              void* d_out, int out_size, void* d_ws, size_t ws_size,
                              hipStream_t stream) {
  const float* pm     = (const float*)d_in[0];  // [B,Q,N]
  const float* logits = (const float*)d_in[1];  // [B,Q,C1]
  const int*   labels = (const int*)d_in[2];    // [B,N]
  const int*   seg    = (const int*)d_in[3];    // [B,N]

  char* w = (char*)d_ws;
  float* fS       = (float*)w; w += (size_t)kB * kQ * kI * 4;
  float* pS       = (float*)w; w += (size_t)kB * kQ * kI * 4;
  float* negTot   = (float*)w; w += (size_t)kB * kQ * 4;
  float* pTot     = (float*)w; w += (size_t)kB * kQ * 4;
  float* costT    = (float*)w; w += (size_t)kB * kI * kQ * 4;
  int*   cntPart  = (int*)w;   w += (size_t)kB * kPB * kI * 4;
  int*   fiPart   = (int*)w;   w += (size_t)kB * kPB * kI * 4;
  int*   idx_q    = (int*)w;   w += (size_t)kB * kI * 4;

  prep_kernel<<<dim3(kPB, kB), 256, 0, stream>>>(labels, cntPart, fiPart);
  bucket_kernel<<<dim3(kQ, kB), 1024, 0, stream>>>(pm, labels, cntPart, fS, pS,
                                                   negTot, pTot, costT);
  hungarian_kernel<<<kB, 64, 0, stream>>>(costT, idx_q);
  loss_kernel<<<1, 128, 0, stream>>>(logits, seg, fS, pS, negTot, pTot,
                                     cntPart, fiPart, idx_q, (float*)d_out);
}